// Round 13
// baseline (222.086 us; speedup 1.0000x reference)
//
#include <hip/hip_runtime.h>

typedef __attribute__((ext_vector_type(8))) __bf16 bf16x8;
typedef __attribute__((ext_vector_type(8))) unsigned short ushort8v;
typedef __attribute__((ext_vector_type(4))) float f32x4;
typedef __attribute__((ext_vector_type(4))) unsigned int u32x4;

__device__ __forceinline__ unsigned short f2bf(float f) {
  return __builtin_bit_cast(unsigned short, (__bf16)f);
}
__device__ __forceinline__ unsigned int pk2(float a, float b) {
  return (unsigned int)f2bf(a) | ((unsigned int)f2bf(b) << 16);
}

// C-frag pair -> A-operand frag (hardware-verified in r5/r9: both passed the harness).
// cA holds k-local 0..15 at (l4*4+rr), cB k-local 16..31, surviving index in l15.
__device__ __forceinline__ bf16x8 conv_pair(f32x4 cA, f32x4 cB, int lane) {
  unsigned pA0 = pk2(cA[0], cA[1]);
  unsigned pA1 = pk2(cA[2], cA[3]);
  unsigned pB0 = pk2(cB[0], cB[1]);
  unsigned pB1 = pk2(cB[2], cB[3]);
  const int srcA = (lane & 15) + ((lane & 16) << 1);
  const int srcB = srcA + 16;
  const bool hi = (lane & 32) != 0;
  unsigned d0a = __shfl((int)pA0, srcA, 64), d0b = __shfl((int)pB0, srcA, 64);
  unsigned d1a = __shfl((int)pA1, srcA, 64), d1b = __shfl((int)pB1, srcA, 64);
  unsigned d2a = __shfl((int)pA0, srcB, 64), d2b = __shfl((int)pB0, srcB, 64);
  unsigned d3a = __shfl((int)pA1, srcB, 64), d3b = __shfl((int)pB1, srcB, 64);
  u32x4 dd;
  dd[0] = hi ? d0b : d0a; dd[1] = hi ? d1b : d1a;
  dd[2] = hi ? d2b : d2a; dd[3] = hi ? d3b : d3a;
  return __builtin_bit_cast(bf16x8, dd);
}

// Swizzled byte offsets (XOR row-bits into the 16B-slot index -> no bank conflicts, G4)
__device__ __forceinline__ int qoff(int row, int colb) {  // 256B rows (A/Q/K[64][128] bf16)
  return row * 256 + (colb ^ ((row & 7) << 4));
}
__device__ __forceinline__ int toff(int row, int colb) {  // 128B rows (S[64][64] bf16)
  return row * 128 + (colb ^ ((row & 7) << 4));
}

// Barrier that does NOT drain vmcnt: LDS-ordering only (m201-verified pattern).
__device__ __forceinline__ void bar_lds() {
  asm volatile("s_waitcnt lgkmcnt(0)" ::: "memory");
  __builtin_amdgcn_s_barrier();
}

__global__ void prep_w(const float* __restrict__ Wq, const float* __restrict__ Wk,
                       const float* __restrict__ Wv, unsigned short* __restrict__ ws) {
  int i = blockIdx.x * 256 + threadIdx.x;
  if (i >= 3 * 16384) return;
  const float* s = (i < 16384) ? Wq : (i < 32768 ? Wk : Wv);
  ws[i] = f2bf(s[i & 16383]);
}

// 16 rows/block, grid 512, 1024 threads = 16 waves FORCED co-resident (4 waves/SIMD —
// the TLP that 8-wave blocks never got; occupancy counters showed 1 block/CU).
// Producer/consumer wave-group pipeline, one lgkm-only barrier per step:
//   group A (waves 0-7)  @ step t:  xr-pref(t-2) || G_QK(t)[t&1] || G_V(t)->av regs
//                                   || P(t-2) [sS/pPart (t&1)] + out stores
//   group B (waves 8-15) @ step t:  S(t-1)[(t-1)&1] || H(t+1)->sA[(t+1)&1]
//                                   || lnred(t+2) || x-load(t+3)
// V never touches LDS (conv_pair into A-operand regs, r5/r9-verified; av held 2 steps).
// Parity audit: every cross-group pair (sA: B-write/A-read; sQ,sK: A-write/B-read;
// sS,pPart: B-write/A-read; redS: B-internal) alternates parity and crosses >=1
// {lgkmcnt(0)+s_barrier}. Barrier counts match across groups (20 each).
__global__ __launch_bounds__(1024, 1) void fused_attn(
    const float* __restrict__ x, const unsigned short* __restrict__ wsW,
    const float* __restrict__ bq, const float* __restrict__ bk, const float* __restrict__ bv,
    const float* __restrict__ ln_w, const float* __restrict__ ln_b,
    float* __restrict__ out) {
  __shared__ __align__(16) unsigned char smem[115840];
  // sA[p]=p*16384; sQ[p]=32768+p*16384; sK[p]=65536+p*16384; sS[p]=98304+p*8192
  float* redS  = (float*)(smem + 114688);   // [2][16]
  float* pPart = (float*)(smem + 114816);   // [2][8][16]

  const int tid = threadIdx.x;
  const int lane = tid & 63;
  const int w = tid >> 6;            // 0..15
  const int wl = w & 7;
  const int l15 = lane & 15;
  const int l4 = lane >> 4;
  const size_t base = (size_t)blockIdx.x * (16 * 8192);

  if (w < 8) {
    // ==================== GROUP A ====================
    const int col = (wl << 4) + l15;
    bf16x8 wfq[4], wfk[4];
    {
      const unsigned short* wpq = wsW + col * 128 + (l4 << 3);
      const unsigned short* wpk = wsW + 16384 + col * 128 + (l4 << 3);
#pragma unroll
      for (int kk = 0; kk < 4; ++kk) {
        wfq[kk] = *(const bf16x8*)(wpq + kk * 32);
        wfk[kk] = *(const bf16x8*)(wpk + kk * 32);
      }
    }
    const float biasQ = bq[col], biasK = bk[col], biasV = bv[col];
    bar_lds();  // match B prologue ph1
    bar_lds();  // match B prologue ph2

    bf16x8 avP[2], avPP[2];
#pragma unroll 1
    for (int t = 0; t < 18; ++t) {
      const int cur = t & 1;
      unsigned char* sAc = smem + cur * 16384;
      unsigned char* sQc = smem + 32768 + cur * 16384;
      unsigned char* sKc = smem + 65536 + cur * 16384;
      unsigned char* sSp = smem + 98304 + cur * 8192;  // (t-2)&1 == cur
      float* pPp = pPart + cur * 128;

      f32x4 xrP[4];
      if (t >= 2) {  // residual prefetch for P(t-2); in flight under G
        const size_t bofsP = base + (size_t)(t - 2) * 8192;
#pragma unroll
        for (int nt = 0; nt < 4; ++nt) {
          const int l = nt * 16 + l15;
          const int mb = (wl << 4) + (l4 << 2);
          xrP[nt] = *(const f32x4*)(x + bofsP + (size_t)l * 128 + mb);
        }
      }
      bf16x8 avN[2];
      if (t <= 15) {
        // G_QK(t)
#pragma unroll
        for (int mt = 0; mt < 4; ++mt) {
          bf16x8 aq[4];
#pragma unroll
          for (int kk = 0; kk < 4; ++kk)
            aq[kk] = *(const bf16x8*)(sAc + qoff(mt * 16 + l15, kk * 64 + (l4 << 4)));
          const int i0m = mt * 16 + (l4 << 2);
          f32x4 aQ = {0,0,0,0}, aK = {0,0,0,0};
#pragma unroll
          for (int kk = 0; kk < 4; ++kk) {
            aQ = __builtin_amdgcn_mfma_f32_16x16x32_bf16(aq[kk], wfq[kk], aQ, 0, 0, 0);
            aK = __builtin_amdgcn_mfma_f32_16x16x32_bf16(aq[kk], wfk[kk], aK, 0, 0, 0);
          }
#pragma unroll
          for (int rr = 0; rr < 4; ++rr) {
            float zq = aQ[rr] + biasQ; zq = zq > 0.f ? zq + 1.f : __expf(zq);
            *(unsigned short*)(sQc + qoff(i0m + rr, col * 2)) = f2bf(zq);
            float zk = aK[rr] + biasK; zk = zk > 0.f ? zk + 1.f : __expf(zk);
            *(unsigned short*)(sKc + qoff(i0m + rr, col * 2)) = f2bf(zk);
          }
        }
        // G_V(t) -> avN (registers only; r5-verified shuffle)
        bf16x8 wfv[4];
        const unsigned short* wpv = wsW + 2 * 16384 + col * 128 + (l4 << 3);
#pragma unroll
        for (int kk = 0; kk < 4; ++kk)
          wfv[kk] = *(const bf16x8*)(wpv + kk * 32);
#pragma unroll
        for (int kf = 0; kf < 2; ++kf) {
          f32x4 aV0 = {0,0,0,0}, aV1 = {0,0,0,0};
#pragma unroll
          for (int kk = 0; kk < 4; ++kk) {
            bf16x8 aq0 = *(const bf16x8*)(sAc + qoff((2*kf) * 16 + l15, kk * 64 + (l4 << 4)));
            aV0 = __builtin_amdgcn_mfma_f32_16x16x32_bf16(aq0, wfv[kk], aV0, 0, 0, 0);
          }
#pragma unroll
          for (int kk = 0; kk < 4; ++kk) {
            bf16x8 aq1 = *(const bf16x8*)(sAc + qoff((2*kf+1) * 16 + l15, kk * 64 + (l4 << 4)));
            aV1 = __builtin_amdgcn_mfma_f32_16x16x32_bf16(aq1, wfv[kk], aV1, 0, 0, 0);
          }
          f32x4 y0, y1;
#pragma unroll
          for (int rr = 0; rr < 4; ++rr) {
            y0[rr] = aV0[rr] + biasV;
            y1[rr] = aV1[rr] + biasV;
          }
          avN[kf] = conv_pair(y0, y1, lane);
        }
      }
      if (t >= 2) {
        // P(t-2): PV + residual + store (av from 2 steps ago)
        const size_t bofsP = base + (size_t)(t - 2) * 8192;
        float nv[4];
#pragma unroll
        for (int nt = 0; nt < 4; ++nt)
          nv[nt] = 1.f / (pPp[nt * 32 + l15] + pPp[nt * 32 + 16 + l15] + 1e-7f);
#pragma unroll
        for (int nt = 0; nt < 4; ++nt) {
          bf16x8 bs0 = *(const bf16x8*)(sSp + toff(nt * 16 + l15, (l4 << 4)));
          bf16x8 bs1 = *(const bf16x8*)(sSp + toff(nt * 16 + l15, 64 + (l4 << 4)));
          f32x4 acc = {0,0,0,0};
          acc = __builtin_amdgcn_mfma_f32_16x16x32_bf16(avPP[0], bs0, acc, 0, 0, 0);
          acc = __builtin_amdgcn_mfma_f32_16x16x32_bf16(avPP[1], bs1, acc, 0, 0, 0);
          const int l = nt * 16 + l15;
          const int mb = (wl << 4) + (l4 << 2);
          const size_t idx = bofsP + (size_t)l * 128 + mb;
          f32x4 o;
          o[0] = acc[0] * nv[nt] + xrP[nt][0];
          o[1] = acc[1] * nv[nt] + xrP[nt][1];
          o[2] = acc[2] * nv[nt] + xrP[nt][2];
          o[3] = acc[3] * nv[nt] + xrP[nt][3];
          *(f32x4*)(out + idx) = o;
        }
      }
      avPP[0] = avP[0]; avPP[1] = avP[1];
      avP[0] = avN[0];  avP[1] = avN[1];
      bar_lds();
    }
  } else {
    // ==================== GROUP B ====================
    const int tidB = tid & 511;
    const int row_x = tidB >> 3;       // 0..63
    const int c0 = (tidB & 7) << 4;    // 0..112
    float lw[16], lb[16];
    {
      const float* pw = ln_w + row_x * 128 + c0;
      const float* pb = ln_b + row_x * 128 + c0;
#pragma unroll
      for (int i = 0; i < 4; ++i) {
        float4 a = *(const float4*)(pw + i * 4);
        lw[i*4+0]=a.x; lw[i*4+1]=a.y; lw[i*4+2]=a.z; lw[i*4+3]=a.w;
        float4 b = *(const float4*)(pb + i * 4);
        lb[i*4+0]=b.x; lb[i*4+1]=b.y; lb[i*4+2]=b.z; lb[i*4+3]=b.w;
      }
    }
    float xv0[16], xv1[16];
    // ---- prologue ph1: load rows 0,1; reduce row0 -> redS[parity0] ----
    {
      const float* xp0 = x + base + (size_t)row_x * 128 + c0;
      const float* xp1 = xp0 + 8192;
#pragma unroll
      for (int i = 0; i < 4; ++i) {
        float4 a = *(const float4*)(xp0 + i * 4);
        xv0[i*4+0]=a.x; xv0[i*4+1]=a.y; xv0[i*4+2]=a.z; xv0[i*4+3]=a.w;
        float4 b = *(const float4*)(xp1 + i * 4);
        xv1[i*4+0]=b.x; xv1[i*4+1]=b.y; xv1[i*4+2]=b.z; xv1[i*4+3]=b.w;
      }
      float s1 = 0.f, s2 = 0.f;
#pragma unroll
      for (int i = 0; i < 16; ++i) { s1 += xv0[i]; s2 += xv0[i] * xv0[i]; }
#pragma unroll
      for (int off = 32; off > 0; off >>= 1) {
        s1 += __shfl_xor(s1, off, 64);
        s2 += __shfl_xor(s2, off, 64);
      }
      if (lane == 0) { redS[wl] = s1; redS[8 + wl] = s2; }
    }
    bar_lds();
    // ---- prologue ph2: H(0) -> sA[0]; reduce row1 -> redS[parity1]; load row2 -> xv0 ----
    {
      float t1 = 0.f, t2 = 0.f;
#pragma unroll
      for (int p = 0; p < 8; ++p) { t1 += redS[p]; t2 += redS[8 + p]; }
      const float mu = t1 * (1.f / 8192.f);
      const float rstd = rsqrtf(t2 * (1.f / 8192.f) - mu * mu + 1e-5f);
      unsigned char* sA0 = smem;
#pragma unroll
      for (int h = 0; h < 2; ++h) {
        ushort8v tt;
#pragma unroll
        for (int j = 0; j < 8; ++j)
          tt[j] = f2bf((xv0[h*8+j] - mu) * rstd * lw[h*8+j] + lb[h*8+j]);
        *(ushort8v*)(sA0 + qoff(row_x, (c0 << 1) + h * 16)) = tt;
      }
      float n1 = 0.f, n2 = 0.f;
#pragma unroll
      for (int i = 0; i < 16; ++i) { n1 += xv1[i]; n2 += xv1[i] * xv1[i]; }
#pragma unroll
      for (int off = 32; off > 0; off >>= 1) {
        n1 += __shfl_xor(n1, off, 64);
        n2 += __shfl_xor(n2, off, 64);
      }
      if (lane == 0) { redS[16 + wl] = n1; redS[24 + wl] = n2; }
      const float* xp2 = x + base + 2 * 8192 + (size_t)row_x * 128 + c0;
#pragma unroll
      for (int i = 0; i < 4; ++i) {
        float4 a = *(const float4*)(xp2 + i * 4);
        xv0[i*4+0]=a.x; xv0[i*4+1]=a.y; xv0[i*4+2]=a.z; xv0[i*4+3]=a.w;
      }
    }
    bar_lds();

    const int rt = wl >> 1;
    const int h2 = wl & 1;
    const int i0s = rt * 16 + (l4 << 2);
#pragma unroll 1
    for (int t = 0; t < 18; ++t) {
      // ---- S(t-1): QK^T -> raw sS + pPart (parity (t-1)&1) ----
      if (t >= 1 && t <= 16) {
        const int sp = (t - 1) & 1;
        unsigned char* sQp = smem + 32768 + sp * 16384;
        unsigned char* sKp = smem + 65536 + sp * 16384;
        unsigned char* sSp = smem + 98304 + sp * 8192;
        float* pPp = pPart + sp * 128;
        bf16x8 aq[4];
#pragma unroll
        for (int kk = 0; kk < 4; ++kk)
          aq[kk] = *(const bf16x8*)(sQp + qoff(rt * 16 + l15, kk * 64 + (l4 << 4)));
        f32x4 accS[2];
#pragma unroll
        for (int nt = 0; nt < 2; ++nt) {
          const int ntg = h2 * 2 + nt;
          f32x4 acc = {0,0,0,0};
#pragma unroll
          for (int kk = 0; kk < 4; ++kk) {
            bf16x8 bk_ = *(const bf16x8*)(sKp + qoff(ntg * 16 + l15, kk * 64 + (l4 << 4)));
            acc = __builtin_amdgcn_mfma_f32_16x16x32_bf16(aq[kk], bk_, acc, 0, 0, 0);
          }
          accS[nt] = acc;
        }
        float p[4];
#pragma unroll
        for (int rr = 0; rr < 4; ++rr) p[rr] = accS[0][rr] + accS[1][rr];
#pragma unroll
        for (int off = 1; off < 16; off <<= 1) {
#pragma unroll
          for (int rr = 0; rr < 4; ++rr) p[rr] += __shfl_xor(p[rr], off, 64);
        }
        if (l15 == 0) {
#pragma unroll
          for (int rr = 0; rr < 4; ++rr)
            pPp[wl * 16 + (l4 << 2) + rr] = p[rr];
        }
#pragma unroll
        for (int nt = 0; nt < 2; ++nt) {
          const int ntg = h2 * 2 + nt;
#pragma unroll
          for (int rr = 0; rr < 4; ++rr)
            *(unsigned short*)(sSp + toff(i0s + rr, (ntg * 16 + l15) * 2)) = f2bf(accS[nt][rr]);
        }
      }
      // ---- H(t+1): pack row t+1 -> sA[(t+1)&1]; consumes xv[(t+1)&1] ----
      if (t <= 14) {
        const int hp = (t + 1) & 1;
        const float* rp = redS + hp * 16;
        float t1 = 0.f, t2 = 0.f;
#pragma unroll
        for (int p = 0; p < 8; ++p) { t1 += rp[p]; t2 += rp[8 + p]; }
        const float mu = t1 * (1.f / 8192.f);
        const float rstd = rsqrtf(t2 * (1.f / 8192.f) - mu * mu + 1e-5f);
        unsigned char* sAn = smem + hp * 16384;
        if (hp) {
#pragma unroll
          for (int h = 0; h < 2; ++h) {
            ushort8v tt;
#pragma unroll
            for (int j = 0; j < 8; ++j)
              tt[j] = f2bf((xv1[h*8+j] - mu) * rstd * lw[h*8+j] + lb[h*8+j]);
            *(ushort8v*)(sAn + qoff(row_x, (c0 << 1) + h * 16)) = tt;
          }
        } else {
#pragma unroll
          for (int h = 0; h < 2; ++h) {
            ushort8v tt;
#pragma unroll
            for (int j = 0; j < 8; ++j)
              tt[j] = f2bf((xv0[h*8+j] - mu) * rstd * lw[h*8+j] + lb[h*8+j]);
            *(ushort8v*)(sAn + qoff(row_x, (c0 << 1) + h * 16)) = tt;
          }
        }
      }
      // ---- lnred(t+2): reduce xv[t&1] -> redS[t&1] ----
      if (t <= 13) {
        float n1 = 0.f, n2 = 0.f;
        if (t & 1) {
#pragma unroll
          for (int i = 0; i < 16; ++i) { n1 += xv1[i]; n2 += xv1[i] * xv1[i]; }
        } else {
#pragma unroll
          for (int i = 0; i < 16; ++i) { n1 += xv0[i]; n2 += xv0[i] * xv0[i]; }
        }
#pragma unroll
        for (int off = 32; off > 0; off >>= 1) {
          n1 += __shfl_xor(n1, off, 64);
          n2 += __shfl_xor(n2, off, 64);
        }
        if (lane == 0) {
          float* nb = redS + (t & 1) * 16;
          nb[wl] = n1; nb[8 + wl] = n2;
        }
      }
      // ---- load row t+3 -> xv[(t+1)&1] (slot just freed by H(t+1)) ----
      if (t <= 12) {
        const float* xp = x + base + (size_t)(t + 3) * 8192 + (size_t)row_x * 128 + c0;
        if ((t + 1) & 1) {
#pragma unroll
          for (int i = 0; i < 4; ++i) {
            float4 a = *(const float4*)(xp + i * 4);
            xv1[i*4+0]=a.x; xv1[i*4+1]=a.y; xv1[i*4+2]=a.z; xv1[i*4+3]=a.w;
          }
        } else {
#pragma unroll
          for (int i = 0; i < 4; ++i) {
            float4 a = *(const float4*)(xp + i * 4);
            xv0[i*4+0]=a.x; xv0[i*4+1]=a.y; xv0[i*4+2]=a.z; xv0[i*4+3]=a.w;
          }
        }
      }
      bar_lds();
    }
  }
}

extern "C" void kernel_launch(void* const* d_in, const int* in_sizes, int n_in,
                              void* d_out, int out_size, void* d_ws, size_t ws_size,
                              hipStream_t stream) {
  const float* x   = (const float*)d_in[0];
  const float* Wq  = (const float*)d_in[1];
  const float* bq  = (const float*)d_in[2];
  const float* Wk  = (const float*)d_in[3];
  const float* bk  = (const float*)d_in[4];
  const float* Wv  = (const float*)d_in[5];
  const float* bv  = (const float*)d_in[6];
  const float* lnw = (const float*)d_in[7];
  const float* lnb = (const float*)d_in[8];
  unsigned short* ws = (unsigned short*)d_ws;  // 96 KB bf16 weights
  float* out = (float*)d_out;

  prep_w<<<192, 256, 0, stream>>>(Wq, Wk, Wv, ws);
  fused_attn<<<512, 1024, 0, stream>>>(x, ws, bq, bk, bv, lnw, lnb, out);
}

// Round 14
// 177.113 us; speedup vs baseline: 1.2539x; 1.2539x over previous
//
#include <hip/hip_runtime.h>

typedef __attribute__((ext_vector_type(8))) __bf16 bf16x8;
typedef __attribute__((ext_vector_type(8))) unsigned short ushort8v;
typedef __attribute__((ext_vector_type(4))) float f32x4;

__device__ __forceinline__ unsigned short f2bf(float f) {
  return __builtin_bit_cast(unsigned short, (__bf16)f);
}

// Swizzled byte offsets (XOR row-bits into the 16B-slot index -> no bank conflicts, G4)
__device__ __forceinline__ int qoff(int row, int colb) {  // 256B rows (A/Q/K[64][128] bf16)
  return row * 256 + (colb ^ ((row & 7) << 4));
}
__device__ __forceinline__ int toff(int row, int colb) {  // 128B rows (VT[128][64], S[64][64] bf16)
  return row * 128 + (colb ^ ((row & 7) << 4));
}

// Barrier that does NOT drain vmcnt: LDS-ordering only (m201-verified pattern).
__device__ __forceinline__ void bar_lds() {
  asm volatile("s_waitcnt lgkmcnt(0)" ::: "memory");
  __builtin_amdgcn_s_barrier();
}

__global__ void prep_w(const float* __restrict__ Wq, const float* __restrict__ Wk,
                       const float* __restrict__ Wv, unsigned short* __restrict__ ws) {
  int i = blockIdx.x * 256 + threadIdx.x;
  if (i >= 3 * 16384) return;
  const float* s = (i < 16384) ? Wq : (i < 32768 ? Wk : Wv);
  ws[i] = f2bf(s[i & 16383]);
}

// 16 rows/block, grid 512 — r11's champion two-row phase-overlapped pipeline with the
// per-block row count doubled (prologue + pipeline fill/drain amortized 2x; the
// 2048x4 -> 1024x8 step of r10 showed this lever is reliably positive). Body is
// byte-identical to r11 (r12/r13 proved body edits regress):
//   IA(r): xr-pref(r-1) || G(r) GEMM1[cur] (48 MFMA) || H(r+1) pack[nxt] || x-load(r+2)
//   IB(r): S(r) QK^T[cur] || lnred(r+2) || P(r-1) PV+store[nxt]
// 2 lgkm-only barriers/row; all LDS double-buffered by row parity (148.6 KB, 1
// block/CU by design — occupancy counters show ~1 block resident regardless).
__global__ __launch_bounds__(512, 1) void fused_attn(
    const float* __restrict__ x, const unsigned short* __restrict__ wsW,
    const float* __restrict__ bq, const float* __restrict__ bk, const float* __restrict__ bv,
    const float* __restrict__ ln_w, const float* __restrict__ ln_b,
    float* __restrict__ out) {
  __shared__ __align__(16) unsigned char smem[148608];
  // sA[p]=p*16384; sQ[p]=32768+p*16384; sK[p]=65536+p*16384; sVT[p]=98304+p*16384;
  // sS[p]=131072+p*8192; redS=[2][16]f @147456; pPart=[2][8][16]f @147584
  float* redS  = (float*)(smem + 147456);
  float* pPart = (float*)(smem + 147584);

  const int tid = threadIdx.x;
  const int lane = tid & 63;
  const int w = tid >> 6;            // wave 0..7
  const int l15 = lane & 15;
  const int l4 = lane >> 4;          // 0..3
  const size_t base = (size_t)blockIdx.x * (16 * 8192);

  // ---- persistent: weights (24 VGPR) + biases + ln slices (32 VGPR) ----
  bf16x8 wf[3][4];
  const int col = (w << 4) + l15;
#pragma unroll
  for (int m = 0; m < 3; ++m) {
    const unsigned short* wp = wsW + m * 16384 + col * 128 + (l4 << 3);
#pragma unroll
    for (int kk = 0; kk < 4; ++kk)
      wf[m][kk] = *(const bf16x8*)(wp + kk * 32);
  }
  const float biasQ = bq[col], biasK = bk[col], biasV = bv[col];

  const int row_x = tid >> 3;        // 0..63
  const int c0 = (tid & 7) << 4;     // 0..112
  float lw[16], lb[16];
  {
    const float* pw = ln_w + row_x * 128 + c0;
    const float* pb = ln_b + row_x * 128 + c0;
#pragma unroll
    for (int i = 0; i < 4; ++i) {
      float4 a = *(const float4*)(pw + i * 4);
      lw[i*4+0]=a.x; lw[i*4+1]=a.y; lw[i*4+2]=a.z; lw[i*4+3]=a.w;
      float4 b = *(const float4*)(pb + i * 4);
      lb[i*4+0]=b.x; lb[i*4+1]=b.y; lb[i*4+2]=b.z; lb[i*4+3]=b.w;
    }
  }

  // ---- prologue: row0 load+reduce; H(0); row1 load+reduce (paid once per 16 rows) ----
  float xvC[16], xvN[16];
  {
    const float* xp = x + base + (size_t)row_x * 128 + c0;
#pragma unroll
    for (int i = 0; i < 4; ++i) {
      float4 a = *(const float4*)(xp + i * 4);
      xvC[i*4+0]=a.x; xvC[i*4+1]=a.y; xvC[i*4+2]=a.z; xvC[i*4+3]=a.w;
    }
  }
  {
    float s1 = 0.f, s2 = 0.f;
#pragma unroll
    for (int i = 0; i < 16; ++i) { s1 += xvC[i]; s2 += xvC[i] * xvC[i]; }
#pragma unroll
    for (int off = 32; off > 0; off >>= 1) {
      s1 += __shfl_xor(s1, off, 64);
      s2 += __shfl_xor(s2, off, 64);
    }
    if (lane == 0) { redS[w] = s1; redS[8 + w] = s2; }
  }
  bar_lds();  // redS[0] visible
  {
    // H(0): pack row0 -> sA[0]
    float t1 = 0.f, t2 = 0.f;
#pragma unroll
    for (int p = 0; p < 8; ++p) { t1 += redS[p]; t2 += redS[8 + p]; }
    const float mu = t1 * (1.f / 8192.f);
    const float rstd = rsqrtf(t2 * (1.f / 8192.f) - mu * mu + 1e-5f);
    unsigned char* sA0 = smem;
#pragma unroll
    for (int h = 0; h < 2; ++h) {
      ushort8v t;
#pragma unroll
      for (int j = 0; j < 8; ++j)
        t[j] = f2bf((xvC[h*8+j] - mu) * rstd * lw[h*8+j] + lb[h*8+j]);
      *(ushort8v*)(sA0 + qoff(row_x, (c0 << 1) + h * 16)) = t;
    }
    // load row1 + its reduce (exposed once per block)
    const float* xp = x + base + 8192 + (size_t)row_x * 128 + c0;
#pragma unroll
    for (int i = 0; i < 4; ++i) {
      float4 a = *(const float4*)(xp + i * 4);
      xvN[i*4+0]=a.x; xvN[i*4+1]=a.y; xvN[i*4+2]=a.z; xvN[i*4+3]=a.w;
    }
    float s1 = 0.f, s2 = 0.f;
#pragma unroll
    for (int i = 0; i < 16; ++i) { s1 += xvN[i]; s2 += xvN[i] * xvN[i]; }
#pragma unroll
    for (int off = 32; off > 0; off >>= 1) {
      s1 += __shfl_xor(s1, off, 64);
      s2 += __shfl_xor(s2, off, 64);
    }
    if (lane == 0) { redS[16 + w] = s1; redS[24 + w] = s2; }
  }
  bar_lds();  // sA[0] + redS[1] visible
#pragma unroll
  for (int i = 0; i < 16; ++i) xvC[i] = xvN[i];  // xvC = row1

#pragma unroll 1
  for (int r = 0; r < 16; ++r) {
    const int cur = r & 1, nxt = cur ^ 1;
    unsigned char* sAc  = smem + cur * 16384;
    unsigned char* sAn  = smem + nxt * 16384;
    unsigned char* sQc  = smem + 32768 + cur * 16384;
    unsigned char* sKc  = smem + 65536 + cur * 16384;
    unsigned char* sVTc = smem + 98304 + cur * 16384;
    unsigned char* sVTn = smem + 98304 + nxt * 16384;
    unsigned char* sSc  = smem + 131072 + cur * 8192;
    unsigned char* sSn  = smem + 131072 + nxt * 8192;
    float* redC = redS + cur * 16;    // lnred(r+2) target
    float* redN = redS + nxt * 16;    // H(r+1) source
    float* pPc = pPart + cur * 128;
    float* pPn = pPart + nxt * 128;
    const size_t bofs = base + (size_t)r * 8192;

    // ================= IA(r): xr(r-1) prefetch || G(r) || H(r+1) =================
    f32x4 xrP[4];
    if (r >= 1) {
      const size_t bofsP = bofs - 8192;
#pragma unroll
      for (int nt = 0; nt < 4; ++nt) {
        const int l = nt * 16 + l15;
        const int mb = (w << 4) + (l4 << 2);
        xrP[nt] = *(const f32x4*)(x + bofsP + (size_t)l * 128 + mb);
      }
    }
    // G(r): GEMM1 (col-split) from sA[cur]
#pragma unroll
    for (int mt = 0; mt < 4; ++mt) {
      bf16x8 aq[4];
#pragma unroll
      for (int kk = 0; kk < 4; ++kk)
        aq[kk] = *(const bf16x8*)(sAc + qoff(mt * 16 + l15, kk * 64 + (l4 << 4)));
      const int i0m = mt * 16 + (l4 << 2);
      f32x4 aQ = {0,0,0,0}, aK = {0,0,0,0}, aV = {0,0,0,0};
#pragma unroll
      for (int kk = 0; kk < 4; ++kk) {
        aQ = __builtin_amdgcn_mfma_f32_16x16x32_bf16(aq[kk], wf[0][kk], aQ, 0, 0, 0);
        aK = __builtin_amdgcn_mfma_f32_16x16x32_bf16(aq[kk], wf[1][kk], aK, 0, 0, 0);
        aV = __builtin_amdgcn_mfma_f32_16x16x32_bf16(aq[kk], wf[2][kk], aV, 0, 0, 0);
      }
#pragma unroll
      for (int rr = 0; rr < 4; ++rr) {
        float zq = aQ[rr] + biasQ; zq = zq > 0.f ? zq + 1.f : __expf(zq);
        *(unsigned short*)(sQc + qoff(i0m + rr, col * 2)) = f2bf(zq);
        float zk = aK[rr] + biasK; zk = zk > 0.f ? zk + 1.f : __expf(zk);
        *(unsigned short*)(sKc + qoff(i0m + rr, col * 2)) = f2bf(zk);
      }
      ushort4 pk;
      pk.x = f2bf(aV[0] + biasV); pk.y = f2bf(aV[1] + biasV);
      pk.z = f2bf(aV[2] + biasV); pk.w = f2bf(aV[3] + biasV);
      *(ushort4*)(sVTc + toff(col, i0m * 2)) = pk;
    }
    // H(r+1): stats from redS[nxt] (written in IB(r-1)/prologue); pack xvC -> sA[nxt]
    if (r < 15) {
      float t1 = 0.f, t2 = 0.f;
#pragma unroll
      for (int p = 0; p < 8; ++p) { t1 += redN[p]; t2 += redN[8 + p]; }
      const float mu = t1 * (1.f / 8192.f);
      const float rstd = rsqrtf(t2 * (1.f / 8192.f) - mu * mu + 1e-5f);
#pragma unroll
      for (int h = 0; h < 2; ++h) {
        ushort8v t;
#pragma unroll
        for (int j = 0; j < 8; ++j)
          t[j] = f2bf((xvC[h*8+j] - mu) * rstd * lw[h*8+j] + lb[h*8+j]);
        *(ushort8v*)(sAn + qoff(row_x, (c0 << 1) + h * 16)) = t;
      }
      if (r < 14) {  // issue load of row r+2 (reduced in IB(r), packed in IA(r+1))
        const float* xp = x + bofs + 2 * 8192 + (size_t)row_x * 128 + c0;
#pragma unroll
        for (int i = 0; i < 4; ++i) {
          float4 a = *(const float4*)(xp + i * 4);
          xvN[i*4+0]=a.x; xvN[i*4+1]=a.y; xvN[i*4+2]=a.z; xvN[i*4+3]=a.w;
        }
      }
    }
    bar_lds();  // end IA(r)

    // ================= IB(r): S(r) || lnred(r+2) || P(r-1) =================
    // S(r): S = Q K^T from sQ/sK[cur]; rowsum partials -> pPart[cur]; raw S -> sS[cur]
    const int rt = w >> 1;
    const int h2 = w & 1;
    const int i0s = rt * 16 + (l4 << 2);
    {
      bf16x8 aq[4];
#pragma unroll
      for (int kk = 0; kk < 4; ++kk)
        aq[kk] = *(const bf16x8*)(sQc + qoff(rt * 16 + l15, kk * 64 + (l4 << 4)));
      f32x4 accS[2];
#pragma unroll
      for (int nt = 0; nt < 2; ++nt) {
        const int ntg = h2 * 2 + nt;
        f32x4 acc = {0,0,0,0};
#pragma unroll
        for (int kk = 0; kk < 4; ++kk) {
          bf16x8 bk_ = *(const bf16x8*)(sKc + qoff(ntg * 16 + l15, kk * 64 + (l4 << 4)));
          acc = __builtin_amdgcn_mfma_f32_16x16x32_bf16(aq[kk], bk_, acc, 0, 0, 0);
        }
        accS[nt] = acc;
      }
      float p[4];
#pragma unroll
      for (int rr = 0; rr < 4; ++rr) p[rr] = accS[0][rr] + accS[1][rr];
#pragma unroll
      for (int off = 1; off < 16; off <<= 1) {
#pragma unroll
        for (int rr = 0; rr < 4; ++rr) p[rr] += __shfl_xor(p[rr], off, 64);
      }
      if (l15 == 0) {
#pragma unroll
        for (int rr = 0; rr < 4; ++rr)
          pPc[w * 16 + (l4 << 2) + rr] = p[rr];
      }
#pragma unroll
      for (int nt = 0; nt < 2; ++nt) {
        const int ntg = h2 * 2 + nt;
#pragma unroll
        for (int rr = 0; rr < 4; ++rr)
          *(unsigned short*)(sSc + toff(i0s + rr, (ntg * 16 + l15) * 2)) = f2bf(accS[nt][rr]);
      }
    }
    // lnred(r+2): reduce xvN -> redS[cur]
    if (r < 14) {
      float n1 = 0.f, n2 = 0.f;
#pragma unroll
      for (int i = 0; i < 16; ++i) { n1 += xvN[i]; n2 += xvN[i] * xvN[i]; }
#pragma unroll
      for (int off = 32; off > 0; off >>= 1) {
        n1 += __shfl_xor(n1, off, 64);
        n2 += __shfl_xor(n2, off, 64);
      }
      if (lane == 0) { redC[w] = n1; redC[8 + w] = n2; }
    }
    // P(r-1): PV + residual + store from buffers [nxt]
    if (r >= 1) {
      const size_t bofsP = bofs - 8192;
      float nv[4];
#pragma unroll
      for (int nt = 0; nt < 4; ++nt)
        nv[nt] = 1.f / (pPn[nt * 32 + l15] + pPn[nt * 32 + 16 + l15] + 1e-7f);
      bf16x8 av[2];
#pragma unroll
      for (int kk = 0; kk < 2; ++kk)
        av[kk] = *(const bf16x8*)(sVTn + toff((w << 4) + l15, kk * 64 + (l4 << 4)));
#pragma unroll
      for (int nt = 0; nt < 4; ++nt) {
        bf16x8 bs0 = *(const bf16x8*)(sSn + toff(nt * 16 + l15, (l4 << 4)));
        bf16x8 bs1 = *(const bf16x8*)(sSn + toff(nt * 16 + l15, 64 + (l4 << 4)));
        f32x4 acc = {0,0,0,0};
        acc = __builtin_amdgcn_mfma_f32_16x16x32_bf16(av[0], bs0, acc, 0, 0, 0);
        acc = __builtin_amdgcn_mfma_f32_16x16x32_bf16(av[1], bs1, acc, 0, 0, 0);
        const int l = nt * 16 + l15;
        const int mb = (w << 4) + (l4 << 2);
        const size_t idx = bofsP + (size_t)l * 128 + mb;
        f32x4 o;
        o[0] = acc[0] * nv[nt] + xrP[nt][0];
        o[1] = acc[1] * nv[nt] + xrP[nt][1];
        o[2] = acc[2] * nv[nt] + xrP[nt][2];
        o[3] = acc[3] * nv[nt] + xrP[nt][3];
        *(f32x4*)(out + idx) = o;
      }
    }
    bar_lds();  // end IB(r)

    if (r < 14) {
#pragma unroll
      for (int i = 0; i < 16; ++i) xvC[i] = xvN[i];
    }
  }

  // ================= epilogue: P(15) (buffers parity 1) =================
  {
    const size_t bofsP = base + 15 * 8192;
    unsigned char* sVT1 = smem + 98304 + 16384;
    unsigned char* sS1  = smem + 131072 + 8192;
    float* pP1 = pPart + 128;
    f32x4 xr7[4];
#pragma unroll
    for (int nt = 0; nt < 4; ++nt) {
      const int l = nt * 16 + l15;
      const int mb = (w << 4) + (l4 << 2);
      xr7[nt] = *(const f32x4*)(x + bofsP + (size_t)l * 128 + mb);
    }
    float nv[4];
#pragma unroll
    for (int nt = 0; nt < 4; ++nt)
      nv[nt] = 1.f / (pP1[nt * 32 + l15] + pP1[nt * 32 + 16 + l15] + 1e-7f);
    bf16x8 av[2];
#pragma unroll
    for (int kk = 0; kk < 2; ++kk)
      av[kk] = *(const bf16x8*)(sVT1 + toff((w << 4) + l15, kk * 64 + (l4 << 4)));
#pragma unroll
    for (int nt = 0; nt < 4; ++nt) {
      bf16x8 bs0 = *(const bf16x8*)(sS1 + toff(nt * 16 + l15, (l4 << 4)));
      bf16x8 bs1 = *(const bf16x8*)(sS1 + toff(nt * 16 + l15, 64 + (l4 << 4)));
      f32x4 acc = {0,0,0,0};
      acc = __builtin_amdgcn_mfma_f32_16x16x32_bf16(av[0], bs0, acc, 0, 0, 0);
      acc = __builtin_amdgcn_mfma_f32_16x16x32_bf16(av[1], bs1, acc, 0, 0, 0);
      const int l = nt * 16 + l15;
      const int mb = (w << 4) + (l4 << 2);
      const size_t idx = bofsP + (size_t)l * 128 + mb;
      f32x4 o;
      o[0] = acc[0] * nv[nt] + xr7[nt][0];
      o[1] = acc[1] * nv[nt] + xr7[nt][1];
      o[2] = acc[2] * nv[nt] + xr7[nt][2];
      o[3] = acc[3] * nv[nt] + xr7[nt][3];
      *(f32x4*)(out + idx) = o;
    }
  }
}

extern "C" void kernel_launch(void* const* d_in, const int* in_sizes, int n_in,
                              void* d_out, int out_size, void* d_ws, size_t ws_size,
                              hipStream_t stream) {
  const float* x   = (const float*)d_in[0];
  const float* Wq  = (const float*)d_in[1];
  const float* bq  = (const float*)d_in[2];
  const float* Wk  = (const float*)d_in[3];
  const float* bk  = (const float*)d_in[4];
  const float* Wv  = (const float*)d_in[5];
  const float* bv  = (const float*)d_in[6];
  const float* lnw = (const float*)d_in[7];
  const float* lnb = (const float*)d_in[8];
  unsigned short* ws = (unsigned short*)d_ws;  // 96 KB bf16 weights
  float* out = (float*)d_out;

  prep_w<<<192, 256, 0, stream>>>(Wq, Wk, Wv, ws);
  fused_attn<<<512, 512, 0, stream>>>(x, ws, bq, bk, bv, lnw, lnb, out);
}

// Round 15
// 171.162 us; speedup vs baseline: 1.2975x; 1.0348x over previous
//
#include <hip/hip_runtime.h>

typedef __attribute__((ext_vector_type(8))) __bf16 bf16x8;
typedef __attribute__((ext_vector_type(8))) unsigned short ushort8v;
typedef __attribute__((ext_vector_type(4))) float f32x4;

__device__ __forceinline__ unsigned short f2bf(float f) {
  return __builtin_bit_cast(unsigned short, (__bf16)f);
}

// Swizzled byte offsets (XOR row-bits into the 16B-slot index -> no bank conflicts, G4)
__device__ __forceinline__ int qoff(int row, int colb) {  // 256B rows (A/Q/K[64][128] bf16)
  return row * 256 + (colb ^ ((row & 7) << 4));
}
__device__ __forceinline__ int toff(int row, int colb) {  // 128B rows (VT[128][64], S[64][64] bf16)
  return row * 128 + (colb ^ ((row & 7) << 4));
}

// Barrier that does NOT drain vmcnt: LDS-ordering only (m201-verified pattern).
__device__ __forceinline__ void bar_lds() {
  asm volatile("s_waitcnt lgkmcnt(0)" ::: "memory");
  __builtin_amdgcn_s_barrier();
}

__global__ void prep_w(const float* __restrict__ Wq, const float* __restrict__ Wk,
                       const float* __restrict__ Wv, unsigned short* __restrict__ ws) {
  int i = blockIdx.x * 256 + threadIdx.x;
  if (i >= 3 * 16384) return;
  const float* s = (i < 16384) ? Wq : (i < 32768 ? Wk : Wv);
  ws[i] = f2bf(s[i & 16383]);
}

// 32 rows/block, grid 256 (exactly 1 block per CU — no inter-block dispatch gap).
// Third application of the amortization lever (2048x4->1024x8: +5%, ->512x16: +6.7%):
// prologue + pipeline fill/drain halves again to ~3% of block lifetime. Row body is
// byte-identical to the r11/r14 champion two-row phase-overlapped pipeline:
//   IA(r): xr-pref(r-1) || G(r) GEMM1[cur] (48 MFMA) || H(r+1) pack[nxt] || x-load(r+2)
//   IB(r): S(r) QK^T[cur] || lnred(r+2) || P(r-1) PV+store[nxt]
// 2 lgkm-only barriers/row; all LDS double-buffered by row parity (148.6 KB).
// HBM traffic is compulsory-minimal (529 MB); remaining gap is latency exposure.
__global__ __launch_bounds__(512, 1) void fused_attn(
    const float* __restrict__ x, const unsigned short* __restrict__ wsW,
    const float* __restrict__ bq, const float* __restrict__ bk, const float* __restrict__ bv,
    const float* __restrict__ ln_w, const float* __restrict__ ln_b,
    float* __restrict__ out) {
  __shared__ __align__(16) unsigned char smem[148608];
  // sA[p]=p*16384; sQ[p]=32768+p*16384; sK[p]=65536+p*16384; sVT[p]=98304+p*16384;
  // sS[p]=131072+p*8192; redS=[2][16]f @147456; pPart=[2][8][16]f @147584
  float* redS  = (float*)(smem + 147456);
  float* pPart = (float*)(smem + 147584);

  const int tid = threadIdx.x;
  const int lane = tid & 63;
  const int w = tid >> 6;            // wave 0..7
  const int l15 = lane & 15;
  const int l4 = lane >> 4;          // 0..3
  const size_t base = (size_t)blockIdx.x * (32 * 8192);

  // ---- persistent: weights (24 VGPR) + biases + ln slices (32 VGPR) ----
  bf16x8 wf[3][4];
  const int col = (w << 4) + l15;
#pragma unroll
  for (int m = 0; m < 3; ++m) {
    const unsigned short* wp = wsW + m * 16384 + col * 128 + (l4 << 3);
#pragma unroll
    for (int kk = 0; kk < 4; ++kk)
      wf[m][kk] = *(const bf16x8*)(wp + kk * 32);
  }
  const float biasQ = bq[col], biasK = bk[col], biasV = bv[col];

  const int row_x = tid >> 3;        // 0..63
  const int c0 = (tid & 7) << 4;     // 0..112
  float lw[16], lb[16];
  {
    const float* pw = ln_w + row_x * 128 + c0;
    const float* pb = ln_b + row_x * 128 + c0;
#pragma unroll
    for (int i = 0; i < 4; ++i) {
      float4 a = *(const float4*)(pw + i * 4);
      lw[i*4+0]=a.x; lw[i*4+1]=a.y; lw[i*4+2]=a.z; lw[i*4+3]=a.w;
      float4 b = *(const float4*)(pb + i * 4);
      lb[i*4+0]=b.x; lb[i*4+1]=b.y; lb[i*4+2]=b.z; lb[i*4+3]=b.w;
    }
  }

  // ---- prologue: row0 load+reduce; H(0); row1 load+reduce (paid once per 32 rows) ----
  float xvC[16], xvN[16];
  {
    const float* xp = x + base + (size_t)row_x * 128 + c0;
#pragma unroll
    for (int i = 0; i < 4; ++i) {
      float4 a = *(const float4*)(xp + i * 4);
      xvC[i*4+0]=a.x; xvC[i*4+1]=a.y; xvC[i*4+2]=a.z; xvC[i*4+3]=a.w;
    }
  }
  {
    float s1 = 0.f, s2 = 0.f;
#pragma unroll
    for (int i = 0; i < 16; ++i) { s1 += xvC[i]; s2 += xvC[i] * xvC[i]; }
#pragma unroll
    for (int off = 32; off > 0; off >>= 1) {
      s1 += __shfl_xor(s1, off, 64);
      s2 += __shfl_xor(s2, off, 64);
    }
    if (lane == 0) { redS[w] = s1; redS[8 + w] = s2; }
  }
  bar_lds();  // redS[0] visible
  {
    // H(0): pack row0 -> sA[0]
    float t1 = 0.f, t2 = 0.f;
#pragma unroll
    for (int p = 0; p < 8; ++p) { t1 += redS[p]; t2 += redS[8 + p]; }
    const float mu = t1 * (1.f / 8192.f);
    const float rstd = rsqrtf(t2 * (1.f / 8192.f) - mu * mu + 1e-5f);
    unsigned char* sA0 = smem;
#pragma unroll
    for (int h = 0; h < 2; ++h) {
      ushort8v t;
#pragma unroll
      for (int j = 0; j < 8; ++j)
        t[j] = f2bf((xvC[h*8+j] - mu) * rstd * lw[h*8+j] + lb[h*8+j]);
      *(ushort8v*)(sA0 + qoff(row_x, (c0 << 1) + h * 16)) = t;
    }
    // load row1 + its reduce (exposed once per block)
    const float* xp = x + base + 8192 + (size_t)row_x * 128 + c0;
#pragma unroll
    for (int i = 0; i < 4; ++i) {
      float4 a = *(const float4*)(xp + i * 4);
      xvN[i*4+0]=a.x; xvN[i*4+1]=a.y; xvN[i*4+2]=a.z; xvN[i*4+3]=a.w;
    }
    float s1 = 0.f, s2 = 0.f;
#pragma unroll
    for (int i = 0; i < 16; ++i) { s1 += xvN[i]; s2 += xvN[i] * xvN[i]; }
#pragma unroll
    for (int off = 32; off > 0; off >>= 1) {
      s1 += __shfl_xor(s1, off, 64);
      s2 += __shfl_xor(s2, off, 64);
    }
    if (lane == 0) { redS[16 + w] = s1; redS[24 + w] = s2; }
  }
  bar_lds();  // sA[0] + redS[1] visible
#pragma unroll
  for (int i = 0; i < 16; ++i) xvC[i] = xvN[i];  // xvC = row1

#pragma unroll 1
  for (int r = 0; r < 32; ++r) {
    const int cur = r & 1, nxt = cur ^ 1;
    unsigned char* sAc  = smem + cur * 16384;
    unsigned char* sAn  = smem + nxt * 16384;
    unsigned char* sQc  = smem + 32768 + cur * 16384;
    unsigned char* sKc  = smem + 65536 + cur * 16384;
    unsigned char* sVTc = smem + 98304 + cur * 16384;
    unsigned char* sVTn = smem + 98304 + nxt * 16384;
    unsigned char* sSc  = smem + 131072 + cur * 8192;
    unsigned char* sSn  = smem + 131072 + nxt * 8192;
    float* redC = redS + cur * 16;    // lnred(r+2) target
    float* redN = redS + nxt * 16;    // H(r+1) source
    float* pPc = pPart + cur * 128;
    float* pPn = pPart + nxt * 128;
    const size_t bofs = base + (size_t)r * 8192;

    // ================= IA(r): xr(r-1) prefetch || G(r) || H(r+1) =================
    f32x4 xrP[4];
    if (r >= 1) {
      const size_t bofsP = bofs - 8192;
#pragma unroll
      for (int nt = 0; nt < 4; ++nt) {
        const int l = nt * 16 + l15;
        const int mb = (w << 4) + (l4 << 2);
        xrP[nt] = *(const f32x4*)(x + bofsP + (size_t)l * 128 + mb);
      }
    }
    // G(r): GEMM1 (col-split) from sA[cur]
#pragma unroll
    for (int mt = 0; mt < 4; ++mt) {
      bf16x8 aq[4];
#pragma unroll
      for (int kk = 0; kk < 4; ++kk)
        aq[kk] = *(const bf16x8*)(sAc + qoff(mt * 16 + l15, kk * 64 + (l4 << 4)));
      const int i0m = mt * 16 + (l4 << 2);
      f32x4 aQ = {0,0,0,0}, aK = {0,0,0,0}, aV = {0,0,0,0};
#pragma unroll
      for (int kk = 0; kk < 4; ++kk) {
        aQ = __builtin_amdgcn_mfma_f32_16x16x32_bf16(aq[kk], wf[0][kk], aQ, 0, 0, 0);
        aK = __builtin_amdgcn_mfma_f32_16x16x32_bf16(aq[kk], wf[1][kk], aK, 0, 0, 0);
        aV = __builtin_amdgcn_mfma_f32_16x16x32_bf16(aq[kk], wf[2][kk], aV, 0, 0, 0);
      }
#pragma unroll
      for (int rr = 0; rr < 4; ++rr) {
        float zq = aQ[rr] + biasQ; zq = zq > 0.f ? zq + 1.f : __expf(zq);
        *(unsigned short*)(sQc + qoff(i0m + rr, col * 2)) = f2bf(zq);
        float zk = aK[rr] + biasK; zk = zk > 0.f ? zk + 1.f : __expf(zk);
        *(unsigned short*)(sKc + qoff(i0m + rr, col * 2)) = f2bf(zk);
      }
      ushort4 pk;
      pk.x = f2bf(aV[0] + biasV); pk.y = f2bf(aV[1] + biasV);
      pk.z = f2bf(aV[2] + biasV); pk.w = f2bf(aV[3] + biasV);
      *(ushort4*)(sVTc + toff(col, i0m * 2)) = pk;
    }
    // H(r+1): stats from redS[nxt] (written in IB(r-1)/prologue); pack xvC -> sA[nxt]
    if (r < 31) {
      float t1 = 0.f, t2 = 0.f;
#pragma unroll
      for (int p = 0; p < 8; ++p) { t1 += redN[p]; t2 += redN[8 + p]; }
      const float mu = t1 * (1.f / 8192.f);
      const float rstd = rsqrtf(t2 * (1.f / 8192.f) - mu * mu + 1e-5f);
#pragma unroll
      for (int h = 0; h < 2; ++h) {
        ushort8v t;
#pragma unroll
        for (int j = 0; j < 8; ++j)
          t[j] = f2bf((xvC[h*8+j] - mu) * rstd * lw[h*8+j] + lb[h*8+j]);
        *(ushort8v*)(sAn + qoff(row_x, (c0 << 1) + h * 16)) = t;
      }
      if (r < 30) {  // issue load of row r+2 (reduced in IB(r), packed in IA(r+1))
        const float* xp = x + bofs + 2 * 8192 + (size_t)row_x * 128 + c0;
#pragma unroll
        for (int i = 0; i < 4; ++i) {
          float4 a = *(const float4*)(xp + i * 4);
          xvN[i*4+0]=a.x; xvN[i*4+1]=a.y; xvN[i*4+2]=a.z; xvN[i*4+3]=a.w;
        }
      }
    }
    bar_lds();  // end IA(r)

    // ================= IB(r): S(r) || lnred(r+2) || P(r-1) =================
    // S(r): S = Q K^T from sQ/sK[cur]; rowsum partials -> pPart[cur]; raw S -> sS[cur]
    const int rt = w >> 1;
    const int h2 = w & 1;
    const int i0s = rt * 16 + (l4 << 2);
    {
      bf16x8 aq[4];
#pragma unroll
      for (int kk = 0; kk < 4; ++kk)
        aq[kk] = *(const bf16x8*)(sQc + qoff(rt * 16 + l15, kk * 64 + (l4 << 4)));
      f32x4 accS[2];
#pragma unroll
      for (int nt = 0; nt < 2; ++nt) {
        const int ntg = h2 * 2 + nt;
        f32x4 acc = {0,0,0,0};
#pragma unroll
        for (int kk = 0; kk < 4; ++kk) {
          bf16x8 bk_ = *(const bf16x8*)(sKc + qoff(ntg * 16 + l15, kk * 64 + (l4 << 4)));
          acc = __builtin_amdgcn_mfma_f32_16x16x32_bf16(aq[kk], bk_, acc, 0, 0, 0);
        }
        accS[nt] = acc;
      }
      float p[4];
#pragma unroll
      for (int rr = 0; rr < 4; ++rr) p[rr] = accS[0][rr] + accS[1][rr];
#pragma unroll
      for (int off = 1; off < 16; off <<= 1) {
#pragma unroll
        for (int rr = 0; rr < 4; ++rr) p[rr] += __shfl_xor(p[rr], off, 64);
      }
      if (l15 == 0) {
#pragma unroll
        for (int rr = 0; rr < 4; ++rr)
          pPc[w * 16 + (l4 << 2) + rr] = p[rr];
      }
#pragma unroll
      for (int nt = 0; nt < 2; ++nt) {
        const int ntg = h2 * 2 + nt;
#pragma unroll
        for (int rr = 0; rr < 4; ++rr)
          *(unsigned short*)(sSc + toff(i0s + rr, (ntg * 16 + l15) * 2)) = f2bf(accS[nt][rr]);
      }
    }
    // lnred(r+2): reduce xvN -> redS[cur]
    if (r < 30) {
      float n1 = 0.f, n2 = 0.f;
#pragma unroll
      for (int i = 0; i < 16; ++i) { n1 += xvN[i]; n2 += xvN[i] * xvN[i]; }
#pragma unroll
      for (int off = 32; off > 0; off >>= 1) {
        n1 += __shfl_xor(n1, off, 64);
        n2 += __shfl_xor(n2, off, 64);
      }
      if (lane == 0) { redC[w] = n1; redC[8 + w] = n2; }
    }
    // P(r-1): PV + residual + store from buffers [nxt]
    if (r >= 1) {
      const size_t bofsP = bofs - 8192;
      float nv[4];
#pragma unroll
      for (int nt = 0; nt < 4; ++nt)
        nv[nt] = 1.f / (pPn[nt * 32 + l15] + pPn[nt * 32 + 16 + l15] + 1e-7f);
      bf16x8 av[2];
#pragma unroll
      for (int kk = 0; kk < 2; ++kk)
        av[kk] = *(const bf16x8*)(sVTn + toff((w << 4) + l15, kk * 64 + (l4 << 4)));
#pragma unroll
      for (int nt = 0; nt < 4; ++nt) {
        bf16x8 bs0 = *(const bf16x8*)(sSn + toff(nt * 16 + l15, (l4 << 4)));
        bf16x8 bs1 = *(const bf16x8*)(sSn + toff(nt * 16 + l15, 64 + (l4 << 4)));
        f32x4 acc = {0,0,0,0};
        acc = __builtin_amdgcn_mfma_f32_16x16x32_bf16(av[0], bs0, acc, 0, 0, 0);
        acc = __builtin_amdgcn_mfma_f32_16x16x32_bf16(av[1], bs1, acc, 0, 0, 0);
        const int l = nt * 16 + l15;
        const int mb = (w << 4) + (l4 << 2);
        const size_t idx = bofsP + (size_t)l * 128 + mb;
        f32x4 o;
        o[0] = acc[0] * nv[nt] + xrP[nt][0];
        o[1] = acc[1] * nv[nt] + xrP[nt][1];
        o[2] = acc[2] * nv[nt] + xrP[nt][2];
        o[3] = acc[3] * nv[nt] + xrP[nt][3];
        *(f32x4*)(out + idx) = o;
      }
    }
    bar_lds();  // end IB(r)

    if (r < 30) {
#pragma unroll
      for (int i = 0; i < 16; ++i) xvC[i] = xvN[i];
    }
  }

  // ================= epilogue: P(31) (buffers parity 1) =================
  {
    const size_t bofsP = base + 31 * 8192;
    unsigned char* sVT1 = smem + 98304 + 16384;
    unsigned char* sS1  = smem + 131072 + 8192;
    float* pP1 = pPart + 128;
    f32x4 xr7[4];
#pragma unroll
    for (int nt = 0; nt < 4; ++nt) {
      const int l = nt * 16 + l15;
      const int mb = (w << 4) + (l4 << 2);
      xr7[nt] = *(const f32x4*)(x + bofsP + (size_t)l * 128 + mb);
    }
    float nv[4];
#pragma unroll
    for (int nt = 0; nt < 4; ++nt)
      nv[nt] = 1.f / (pP1[nt * 32 + l15] + pP1[nt * 32 + 16 + l15] + 1e-7f);
    bf16x8 av[2];
#pragma unroll
    for (int kk = 0; kk < 2; ++kk)
      av[kk] = *(const bf16x8*)(sVT1 + toff((w << 4) + l15, kk * 64 + (l4 << 4)));
#pragma unroll
    for (int nt = 0; nt < 4; ++nt) {
      bf16x8 bs0 = *(const bf16x8*)(sS1 + toff(nt * 16 + l15, (l4 << 4)));
      bf16x8 bs1 = *(const bf16x8*)(sS1 + toff(nt * 16 + l15, 64 + (l4 << 4)));
      f32x4 acc = {0,0,0,0};
      acc = __builtin_amdgcn_mfma_f32_16x16x32_bf16(av[0], bs0, acc, 0, 0, 0);
      acc = __builtin_amdgcn_mfma_f32_16x16x32_bf16(av[1], bs1, acc, 0, 0, 0);
      const int l = nt * 16 + l15;
      const int mb = (w << 4) + (l4 << 2);
      const size_t idx = bofsP + (size_t)l * 128 + mb;
      f32x4 o;
      o[0] = acc[0] * nv[nt] + xr7[nt][0];
      o[1] = acc[1] * nv[nt] + xr7[nt][1];
      o[2] = acc[2] * nv[nt] + xr7[nt][2];
      o[3] = acc[3] * nv[nt] + xr7[nt][3];
      *(f32x4*)(out + idx) = o;
    }
  }
}

extern "C" void kernel_launch(void* const* d_in, const int* in_sizes, int n_in,
                              void* d_out, int out_size, void* d_ws, size_t ws_size,
                              hipStream_t stream) {
  const float* x   = (const float*)d_in[0];
  const float* Wq  = (const float*)d_in[1];
  const float* bq  = (const float*)d_in[2];
  const float* Wk  = (const float*)d_in[3];
  const float* bk  = (const float*)d_in[4];
  const float* Wv  = (const float*)d_in[5];
  const float* bv  = (const float*)d_in[6];
  const float* lnw = (const float*)d_in[7];
  const float* lnb = (const float*)d_in[8];
  unsigned short* ws = (unsigned short*)d_ws;  // 96 KB bf16 weights
  float* out = (float*)d_out;

  prep_w<<<192, 256, 0, stream>>>(Wq, Wk, Wv, ws);
  fused_attn<<<256, 512, 0, stream>>>(x, ws, bq, bk, bv, lnw, lnb, out);
}